// Round 7
// baseline (1188.119 us; speedup 1.0000x reference)
//
#include <hip/hip_runtime.h>
#include <hip/hip_cooperative_groups.h>

namespace cg = cooperative_groups;

// SparseMCFModel: the GNN is dead code. fw_e = 1/(outdeg(src_e)+1e-9) exactly
// (softmax over per-segment-constant scores). Flow loop collapses to node
// space: r_0 = invdeg; r_{k+1}[n] = relu(sum_{e:dst=n} r_k[src_e] - d0[n]) *
// invdeg[n]; flow[e] = r_10[src[e]]; fw[e] = invdeg[src[e]]; cost = sum flow^2.
//
// R1->R2: no single-address cost atomic; CSR gather spmv.       1268 -> 428 us
// R2->R3: bucket partition (atomic-free except outdeg hist).     428 -> 284 us
// R3->R4: zero global atomics, CHUNK 4096.                       284 -> 219 us
// R4->R5: full counting sort -> CSR-by-dst, atomic-free spmv.    219 -> 220 us
// R5->R6: 8x smaller counts matrix, fused scatter, wave-replicated
//   LDS counters, float2 carry.                                  220 -> 188 us
// R6->R7: the 12-launch serial tail (10 spmv + final + reduce) fused into ONE
//   persistent cooperative kernel (grid.sync between iters): row bounds, d0,
//   invdeg pinned in registers across all 10 iters; first 8 csr indices per
//   lane register-cached (avg degree 16 = 2 lanes x 8 -> most rows never
//   re-read csr_src); plain-float r (4B gathers). count_src+fine_sort fused.
//   17 -> 6 launches. Non-cooperative fallback if coop launch is rejected.

static constexpr int BLK      = 256;
static constexpr int SCAN_BLK = 1024;
static constexpr int CHUNK    = 4096;   // edges per partition block
static constexpr int LB       = 9;      // log2(nodes per bucket)
static constexpr int BN       = 512;    // nodes per bucket

// ---------- build passes ----------

__global__ void hist_kernel(const int* __restrict__ src, const int* __restrict__ dst,
                            int* __restrict__ counts, int E, int B, int nb, int M) {
    extern __shared__ int lh[];              // 4 replicas x [0,B) dst | [B,2B) src
    const int nbins = 2 * B;
    for (int i = threadIdx.x; i < 4 * nbins; i += blockDim.x) lh[i] = 0;
    __syncthreads();
    int* my = lh + (threadIdx.x >> 6) * nbins;
    int base = blockIdx.x * CHUNK;
    int end  = base + CHUNK < E ? base + CHUNK : E;
    int i4beg = base >> 2, i4end = end >> 2;
    for (int i = i4beg + threadIdx.x; i < i4end; i += blockDim.x) {
        int4 s4 = ((const int4*)src)[i];
        int4 d4 = ((const int4*)dst)[i];
        atomicAdd(&my[d4.x >> LB], 1); atomicAdd(&my[B + (s4.x >> LB)], 1);
        atomicAdd(&my[d4.y >> LB], 1); atomicAdd(&my[B + (s4.y >> LB)], 1);
        atomicAdd(&my[d4.z >> LB], 1); atomicAdd(&my[B + (s4.z >> LB)], 1);
        atomicAdd(&my[d4.w >> LB], 1); atomicAdd(&my[B + (s4.w >> LB)], 1);
    }
    if (blockIdx.x == (int)gridDim.x - 1 && threadIdx.x == 0) {   // scalar tail
        for (int e = i4end << 2; e < end; ++e) {
            atomicAdd(&my[dst[e] >> LB], 1);
            atomicAdd(&my[B + (src[e] >> LB)], 1);
        }
    }
    __syncthreads();
    for (int i = threadIdx.x; i < nbins; i += blockDim.x) {
        int s = lh[i] + lh[nbins + i] + lh[2 * nbins + i] + lh[3 * nbins + i];
        if (i < B) counts[i * nb + blockIdx.x] = s;               // bin-major
        else       counts[M + (i - B) * nb + blockIdx.x] = s;
    }
}

__global__ void scan_block_kernel(int* __restrict__ data, int* __restrict__ blocksum, int M2) {
    __shared__ int lds[SCAN_BLK];
    int t = threadIdx.x;
    int i = blockIdx.x * SCAN_BLK + t;
    int v = (i < M2) ? data[i] : 0;
    lds[t] = v;
    __syncthreads();
    for (int off = 1; off < SCAN_BLK; off <<= 1) {
        int tmp = (t >= off) ? lds[t - off] : 0;
        __syncthreads();
        lds[t] += tmp;
        __syncthreads();
    }
    if (i < M2) data[i] = lds[t] - v;
    if (t == SCAN_BLK - 1) blocksum[blockIdx.x] = lds[t];
}

__global__ void scan_partials_kernel(const int* __restrict__ bsum, int* __restrict__ boff, int n) {
    __shared__ int lds[SCAN_BLK];
    __shared__ int carry_s;
    if (threadIdx.x == 0) carry_s = 0;
    __syncthreads();
    for (int base = 0; base < n; base += SCAN_BLK) {
        int i = base + threadIdx.x;
        int v = (i < n) ? bsum[i] : 0;
        lds[threadIdx.x] = v;
        __syncthreads();
        for (int off = 1; off < SCAN_BLK; off <<= 1) {
            int tmp = (threadIdx.x >= off) ? lds[threadIdx.x - off] : 0;
            __syncthreads();
            lds[threadIdx.x] += tmp;
            __syncthreads();
        }
        int incl = lds[threadIdx.x];
        int c = carry_s;
        if (i < n) boff[i] = c + incl - v;
        __syncthreads();
        if (threadIdx.x == SCAN_BLK - 1) carry_s = c + incl;
        __syncthreads();
    }
}

__global__ void fused_scatter_kernel(const int* __restrict__ src, const int* __restrict__ dst,
                                     const int* __restrict__ counts, const int* __restrict__ boff,
                                     unsigned* __restrict__ packed, unsigned short* __restrict__ psrc,
                                     int E, int B, int nb, int M) {
    extern __shared__ int loff[];            // [0,B): dst cursors, [B,2B): src cursors
    int b = blockIdx.x;
    for (int i = threadIdx.x; i < B; i += blockDim.x) {
        int id  = i * nb + b;
        int id2 = M + i * nb + b;
        loff[i]     = counts[id]  + boff[id >> 10];
        loff[B + i] = counts[id2] + boff[id2 >> 10] - E;   // src half starts at E
    }
    __syncthreads();
    int base = b * CHUNK;
    int end  = base + CHUNK < E ? base + CHUNK : E;
    int i4beg = base >> 2, i4end = end >> 2;
    for (int i = i4beg + threadIdx.x; i < i4end; i += blockDim.x) {
        int4 s4 = ((const int4*)src)[i];
        int4 d4 = ((const int4*)dst)[i];
        #pragma unroll
        for (int k = 0; k < 4; ++k) {
            int s = (k == 0) ? s4.x : (k == 1) ? s4.y : (k == 2) ? s4.z : s4.w;
            int d = (k == 0) ? d4.x : (k == 1) ? d4.y : (k == 2) ? d4.z : d4.w;
            int pos = atomicAdd(&loff[d >> LB], 1);
            packed[pos] = (unsigned)s | ((unsigned)(d & (BN - 1)) << 17);
            int pos2 = atomicAdd(&loff[B + (s >> LB)], 1);
            psrc[pos2] = (unsigned short)(s & (BN - 1));
        }
    }
    if (b == (int)gridDim.x - 1 && threadIdx.x == 0) {     // scalar tail
        for (int e = i4end << 2; e < end; ++e) {
            int s = src[e], d = dst[e];
            int pos = atomicAdd(&loff[d >> LB], 1);
            packed[pos] = (unsigned)s | ((unsigned)(d & (BN - 1)) << 17);
            int pos2 = atomicAdd(&loff[B + (s >> LB)], 1);
            psrc[pos2] = (unsigned short)(s & (BN - 1));
        }
    }
}

// Fused: (A) src-bucket count -> invdeg, rA; (B) dst-bucket counting sort ->
// csr_src, row_ptr. One block per bucket, BN threads, 8x replicated counters.
__global__ void bucket_kernel(const unsigned short* __restrict__ psrc,
                              const unsigned* __restrict__ packed,
                              const int* __restrict__ counts, const int* __restrict__ boff,
                              float* __restrict__ invdeg, float* __restrict__ rA,
                              int* __restrict__ csr_src, int* __restrict__ row_ptr,
                              int N, int E, int B, int nb, int M) {
    __shared__ int cnt[8 * BN];
    __shared__ int off[BN];
    int t = threadIdx.x, b = blockIdx.x, w = t >> 6;
    int g = (b << LB) + t;
    // ---- phase A: src fine count -> invdeg, r0
    for (int i = t; i < 8 * BN; i += blockDim.x) cnt[i] = 0;
    __syncthreads();
    int id = M + b * nb;
    int beg = counts[id] + boff[id >> 10] - E;
    int end;
    if (b + 1 < B) { int id2 = M + (b + 1) * nb; end = counts[id2] + boff[id2 >> 10] - E; }
    else end = E;
    for (int e = beg + t; e < end; e += blockDim.x)
        atomicAdd(&cnt[(w << 9) + psrc[e]], 1);
    __syncthreads();
    if (g < N) {
        int tot = 0;
        #pragma unroll
        for (int r = 0; r < 8; ++r) tot += cnt[(r << 9) + t];
        float v = 1.0f / ((float)tot + 1e-9f);
        invdeg[g] = v;
        rA[g] = v;                 // r_0 = 1 * invdeg
    }
    __syncthreads();
    // ---- phase B: dst counting sort
    for (int i = t; i < 8 * BN; i += blockDim.x) cnt[i] = 0;
    __syncthreads();
    id = b * nb;
    beg = counts[id] + boff[id >> 10];
    if (b + 1 < B) { int id2 = (b + 1) * nb; end = counts[id2] + boff[id2 >> 10]; }
    else end = E;
    for (int e = beg + t; e < end; e += blockDim.x)
        atomicAdd(&cnt[(w << 9) + (packed[e] >> 17)], 1);
    __syncthreads();
    int tot = 0;
    #pragma unroll
    for (int r = 0; r < 8; ++r) tot += cnt[(r << 9) + t];
    off[t] = tot;
    __syncthreads();
    for (int s = 1; s < BN; s <<= 1) {            // Hillis-Steele inclusive
        int v = (t >= s) ? off[t - s] : 0;
        __syncthreads();
        off[t] += v;
        __syncthreads();
    }
    int excl = beg + off[t] - tot;
    if (g < N) row_ptr[g] = excl;
    {
        int base2 = excl;                          // per-wave pre-reserved cursors
        #pragma unroll
        for (int r = 0; r < 8; ++r) { int c = cnt[(r << 9) + t]; cnt[(r << 9) + t] = base2; base2 += c; }
    }
    __syncthreads();
    for (int e = beg + t; e < end; e += blockDim.x) {
        unsigned v = packed[e];
        int pos = atomicAdd(&cnt[(w << 9) + (v >> 17)], 1);
        csr_src[pos] = (int)(v & 0x1FFFFu);
    }
    if (b == 0 && t == 0) row_ptr[N] = E;
}

// ---------- persistent cooperative flow loop + final + cost ----------

__global__ void __launch_bounds__(BLK, 4)
flow_loop_kernel(const int* __restrict__ row_ptr, const int* __restrict__ csr_src,
                 const float* __restrict__ d0, const float* __restrict__ invdeg,
                 float* __restrict__ rA, float* __restrict__ rB,
                 const int* __restrict__ src, float* __restrict__ flow,
                 float* __restrict__ fw, float* __restrict__ partials,
                 float* __restrict__ cost, int N, int E) {
    cg::grid_group grid = cg::this_grid();
    const int tid = blockIdx.x * blockDim.x + threadIdx.x;
    const int TT  = gridDim.x * blockDim.x;
    const int n = tid >> 1;
    const int half = tid & 1;
    const bool active = (n < N);

    int lo = 0, hi = 0;
    float dmy = 0.0f, inv = 0.0f;
    if (active) {
        int beg = row_ptr[n], end = row_ptr[n + 1];
        int mid = beg + ((end - beg + 1) >> 1);
        lo = half ? mid : beg;
        hi = half ? end : mid;
        if (half == 0) { dmy = d0[n]; inv = invdeg[n]; }
    }
    // register-cache first 8 csr indices of this lane's half-row
    int nc = hi - lo; if (nc > 8) nc = 8; if (nc < 0) nc = 0;
    int c0 = 0, c1 = 0, c2 = 0, c3 = 0, c4 = 0, c5 = 0, c6 = 0, c7 = 0;
    if (nc > 0) c0 = csr_src[lo];
    if (nc > 1) c1 = csr_src[lo + 1];
    if (nc > 2) c2 = csr_src[lo + 2];
    if (nc > 3) c3 = csr_src[lo + 3];
    if (nc > 4) c4 = csr_src[lo + 4];
    if (nc > 5) c5 = csr_src[lo + 5];
    if (nc > 6) c6 = csr_src[lo + 6];
    if (nc > 7) c7 = csr_src[lo + 7];

    const float* rin = rA;
    float* rout = rB;
    for (int it = 0; it < 10; ++it) {
        float a0 = 0.0f, a1 = 0.0f;
        if (active) {
            if (nc > 0) a0 += rin[c0];
            if (nc > 1) a1 += rin[c1];
            if (nc > 2) a0 += rin[c2];
            if (nc > 3) a1 += rin[c3];
            if (nc > 4) a0 += rin[c4];
            if (nc > 5) a1 += rin[c5];
            if (nc > 6) a0 += rin[c6];
            if (nc > 7) a1 += rin[c7];
            for (int j = lo + 8; j < hi; j += 2) {
                a0 += rin[csr_src[j]];
                if (j + 1 < hi) a1 += rin[csr_src[j + 1]];
            }
        }
        float a = a0 + a1;
        a += __shfl_xor(a, 1, 64);
        if (active && half == 0) {
            float p = a - dmy;
            p = p > 0.0f ? p : 0.0f;
            rout[n] = p * inv;
        }
        grid.sync();
        const float* t = rin; rin = rout; rout = const_cast<float*>(t);
    }
    // final: flow/fw/cost from r_10 (== rin after even # of swaps)
    float f2 = 0.0f;
    const int E4 = E >> 2;
    for (int i = tid; i < E4; i += TT) {
        int4 s4 = ((const int4*)src)[i];
        float a = rin[s4.x], b = rin[s4.y], cc = rin[s4.z], dd = rin[s4.w];
        int e = i << 2;
        flow[e] = a; flow[e + 1] = b; flow[e + 2] = cc; flow[e + 3] = dd;
        fw[e]     = invdeg[s4.x]; fw[e + 1] = invdeg[s4.y];
        fw[e + 2] = invdeg[s4.z]; fw[e + 3] = invdeg[s4.w];
        f2 += a * a + b * b + cc * cc + dd * dd;
    }
    if (tid == 0) {                       // tail (E % 4)
        for (int e = E4 << 2; e < E; ++e) {
            float a = rin[src[e]];
            flow[e] = a; fw[e] = invdeg[src[e]];
            f2 += a * a;
        }
    }
    #pragma unroll
    for (int off = 32; off > 0; off >>= 1) f2 += __shfl_down(f2, off, 64);
    __shared__ float wsum[BLK / 64];
    int lane = threadIdx.x & 63, w = threadIdx.x >> 6;
    if (lane == 0) wsum[w] = f2;
    __syncthreads();
    if (threadIdx.x == 0) {
        float s = 0.0f;
        #pragma unroll
        for (int k = 0; k < BLK / 64; ++k) s += wsum[k];
        partials[blockIdx.x] = s;
    }
    grid.sync();
    if (blockIdx.x == 0) {
        float s = 0.0f;
        for (int i = threadIdx.x; i < (int)gridDim.x; i += blockDim.x) s += partials[i];
        #pragma unroll
        for (int off = 32; off > 0; off >>= 1) s += __shfl_down(s, off, 64);
        __shared__ float wsum2[BLK / 64];
        if (lane == 0) wsum2[w] = s;
        __syncthreads();
        if (threadIdx.x == 0) {
            float t2 = 0.0f;
            #pragma unroll
            for (int k = 0; k < BLK / 64; ++k) t2 += wsum2[k];
            cost[0] = t2;
        }
    }
}

// ---------- non-cooperative fallback ----------

__global__ void spmv_f_kernel(const int* __restrict__ row_ptr, const int* __restrict__ csr_src,
                              const float* __restrict__ r_in, const float* __restrict__ d0,
                              const float* __restrict__ invdeg, float* __restrict__ r_out, int N) {
    int tid = blockIdx.x * blockDim.x + threadIdx.x;
    int n = tid >> 1;
    if (n >= N) return;
    int half = tid & 1;
    int beg = row_ptr[n], end = row_ptr[n + 1];
    int mid = beg + ((end - beg + 1) >> 1);
    int lo = half ? mid : beg;
    int hi = half ? end : mid;
    float a0 = 0.0f, a1 = 0.0f;
    int j = lo;
    for (; j + 1 < hi; j += 2) { a0 += r_in[csr_src[j]]; a1 += r_in[csr_src[j + 1]]; }
    if (j < hi) a0 += r_in[csr_src[j]];
    float a = a0 + a1;
    a += __shfl_xor(a, 1, 64);
    if (half == 0) {
        float p = a - d0[n];
        p = p > 0.0f ? p : 0.0f;
        r_out[n] = p * invdeg[n];
    }
}

__global__ void final_f_kernel(const int* __restrict__ src, const float* __restrict__ r_fin,
                               const float* __restrict__ invdeg, float* __restrict__ flow,
                               float* __restrict__ fw, float* __restrict__ partials, int E) {
    int i = blockIdx.x * blockDim.x + threadIdx.x;
    int E4 = E >> 2;
    float f2 = 0.0f;
    if (i < E4) {
        int4 s4 = ((const int4*)src)[i];
        float a = r_fin[s4.x], b = r_fin[s4.y], c = r_fin[s4.z], d = r_fin[s4.w];
        int e = i << 2;
        flow[e] = a; flow[e + 1] = b; flow[e + 2] = c; flow[e + 3] = d;
        fw[e] = invdeg[s4.x]; fw[e + 1] = invdeg[s4.y];
        fw[e + 2] = invdeg[s4.z]; fw[e + 3] = invdeg[s4.w];
        f2 = a * a + b * b + c * c + d * d;
    }
    if (blockIdx.x == 0 && threadIdx.x == 0) {
        for (int e = E4 << 2; e < E; ++e) {
            float a = r_fin[src[e]];
            flow[e] = a; fw[e] = invdeg[src[e]];
            f2 += a * a;
        }
    }
    #pragma unroll
    for (int off = 32; off > 0; off >>= 1) f2 += __shfl_down(f2, off, 64);
    __shared__ float wsum[BLK / 64];
    int lane = threadIdx.x & 63, w = threadIdx.x >> 6;
    if (lane == 0) wsum[w] = f2;
    __syncthreads();
    if (threadIdx.x == 0) {
        float s = 0.0f;
        #pragma unroll
        for (int k = 0; k < BLK / 64; ++k) s += wsum[k];
        partials[blockIdx.x] = s;
    }
}

__global__ void reduce_cost_kernel(const float* __restrict__ partials, float* __restrict__ cost, int n) {
    float s = 0.0f;
    for (int i = threadIdx.x; i < n; i += blockDim.x) s += partials[i];
    #pragma unroll
    for (int off = 32; off > 0; off >>= 1) s += __shfl_down(s, off, 64);
    __shared__ float wsum[16];
    int lane = threadIdx.x & 63, w = threadIdx.x >> 6;
    if (lane == 0) wsum[w] = s;
    __syncthreads();
    if (threadIdx.x == 0) {
        float t = 0.0f;
        for (int k = 0; k < (int)(blockDim.x / 64); ++k) t += wsum[k];
        cost[0] = t;
    }
}

extern "C" void kernel_launch(void* const* d_in, const int* in_sizes, int n_in,
                              void* d_out, int out_size, void* d_ws, size_t ws_size,
                              hipStream_t stream) {
    const float* demands  = (const float*)d_in[0];
    const int*   edge_src = (const int*)d_in[2];
    const int*   edge_dst = (const int*)d_in[3];
    const int N = in_sizes[0];
    const int E = in_sizes[2];

    float* out  = (float*)d_out;
    float* cost = out;
    float* flow = out + 1;
    float* fw   = out + 1 + E;

    const int B   = (N + BN - 1) >> LB;              // 196 buckets
    const int nb  = (E + CHUNK - 1) / CHUNK;         // 391 partition blocks
    const int M   = B * nb;
    const int M2  = 2 * M;                           // ~153K
    const int nbs = (M2 + SCAN_BLK - 1) / SCAN_BLK;
    const int gridF = ((E >> 2) + BLK - 1) / BLK;
    const int gridS = (2 * N + BLK - 1) / BLK;       // 782 blocks
    const int gridP = gridS > gridF ? gridS : gridF;

    auto align16 = [](size_t x) { return (x + 15) & ~size_t(15); };
    char* ws = (char*)d_ws;
    size_t o = 0;
    float*    invdeg   = (float*)(ws + o);    o += align16((size_t)N * 4);
    float*    rA       = (float*)(ws + o);    o += align16((size_t)N * 4);
    float*    rB       = (float*)(ws + o);    o += align16((size_t)N * 4);
    int*      row_ptr  = (int*)(ws + o);      o += align16((size_t)(N + 1) * 4);
    int*      counts   = (int*)(ws + o);      o += align16((size_t)M2 * 4);
    int*      blocksum = (int*)(ws + o);      o += align16((size_t)nbs * 4);
    int*      blockoff = (int*)(ws + o);      o += align16((size_t)nbs * 4);
    unsigned* packed   = (unsigned*)(ws + o); o += align16((size_t)E * 4);
    unsigned short* psrc = (unsigned short*)(ws + o); o += align16((size_t)E * 2);
    int*      csr_src  = (int*)(ws + o);      o += align16((size_t)E * 4);
    float*    partials = (float*)(ws + o);    o += align16((size_t)gridP * 4);

    hist_kernel<<<nb, BLK, (size_t)(8 * B) * 4, stream>>>(edge_src, edge_dst, counts, E, B, nb, M);
    scan_block_kernel<<<nbs, SCAN_BLK, 0, stream>>>(counts, blocksum, M2);
    scan_partials_kernel<<<1, SCAN_BLK, 0, stream>>>(blocksum, blockoff, nbs);
    fused_scatter_kernel<<<nb, BLK, (size_t)(2 * B) * 4, stream>>>(
        edge_src, edge_dst, counts, blockoff, packed, psrc, E, B, nb, M);
    bucket_kernel<<<B, BN, 0, stream>>>(psrc, packed, counts, blockoff,
                                        invdeg, rA, csr_src, row_ptr, N, E, B, nb, M);

    int N_ = N, E_ = E;
    void* args[] = { (void*)&row_ptr, (void*)&csr_src, (void*)&demands, (void*)&invdeg,
                     (void*)&rA, (void*)&rB, (void*)&edge_src, (void*)&flow, (void*)&fw,
                     (void*)&partials, (void*)&cost, (void*)&N_, (void*)&E_ };
    hipError_t err = hipLaunchCooperativeKernel((const void*)flow_loop_kernel,
                                                dim3(gridS), dim3(BLK), args, 0, stream);
    if (err != hipSuccess) {
        // fallback: separate-kernel flow loop (same math)
        float* r_cur = rA;
        float* r_nxt = rB;
        for (int it = 0; it < 10; ++it) {
            spmv_f_kernel<<<gridS, BLK, 0, stream>>>(row_ptr, csr_src, r_cur, demands, invdeg, r_nxt, N);
            float* t = r_cur; r_cur = r_nxt; r_nxt = t;
        }
        final_f_kernel<<<gridF, BLK, 0, stream>>>(edge_src, r_cur, invdeg, flow, fw, partials, E);
        reduce_cost_kernel<<<1, 1024, 0, stream>>>(partials, cost, gridF);
    }
}

// Round 8
// 229.786 us; speedup vs baseline: 5.1706x; 5.1706x over previous
//
#include <hip/hip_runtime.h>

// SparseMCFModel: the GNN is dead code. fw_e = 1/(outdeg(src_e)+1e-9) exactly
// (softmax over per-segment-constant scores). Flow loop collapses to node
// space: r_0 = invdeg; r_{k+1}[n] = relu(sum_{e:dst=n} r_k[src_e] - d0[n]) *
// invdeg[n]; flow[e] = r_10[src[e]]; fw[e] = invdeg[src[e]]; cost = sum flow^2.
//
// R1->R2: no single-address cost atomic; CSR gather spmv.       1268 -> 428 us
// R2->R3: bucket partition (atomic-free except outdeg hist).     428 -> 284 us
// R3->R4: zero global atomics, CHUNK 4096.                       284 -> 219 us
// R4->R5: full counting sort -> CSR-by-dst, atomic-free spmv.    219 -> 220 us
// R5->R6: 8x smaller counts matrix, fused scatter, replicated
//   LDS counters, fused bucket pass.                             220 -> 188 us
// R6->R7: cooperative grid.sync flow loop — REGRESSION: each grid.sync is
//   ~100us on MI355X (cross-XCD L2 non-coherence forces fence+writeback;
//   782 blocks spin one coherent line).                          188 -> 1188 us
// R7->R8: revert to multi-kernel flow loop (launch boundary ~2us << cg sync).
//   Keep fused bucket kernel + plain-float r. New: QUAD-lane spmv (4 lanes/
//   node = 400K threads, ~4 gathers/lane, 2-step shfl_xor) for latency
//   hiding; final+cost fused via threadfence last-block-done ticket.

static constexpr int BLK      = 256;
static constexpr int SCAN_BLK = 1024;
static constexpr int CHUNK    = 4096;   // edges per partition block
static constexpr int LB       = 9;      // log2(nodes per bucket)
static constexpr int BN       = 512;    // nodes per bucket

// ---------- build passes ----------

__global__ void hist_kernel(const int* __restrict__ src, const int* __restrict__ dst,
                            int* __restrict__ counts, int E, int B, int nb, int M) {
    extern __shared__ int lh[];              // 4 replicas x [0,B) dst | [B,2B) src
    const int nbins = 2 * B;
    for (int i = threadIdx.x; i < 4 * nbins; i += blockDim.x) lh[i] = 0;
    __syncthreads();
    int* my = lh + (threadIdx.x >> 6) * nbins;
    int base = blockIdx.x * CHUNK;
    int end  = base + CHUNK < E ? base + CHUNK : E;
    int i4beg = base >> 2, i4end = end >> 2;
    for (int i = i4beg + threadIdx.x; i < i4end; i += blockDim.x) {
        int4 s4 = ((const int4*)src)[i];
        int4 d4 = ((const int4*)dst)[i];
        atomicAdd(&my[d4.x >> LB], 1); atomicAdd(&my[B + (s4.x >> LB)], 1);
        atomicAdd(&my[d4.y >> LB], 1); atomicAdd(&my[B + (s4.y >> LB)], 1);
        atomicAdd(&my[d4.z >> LB], 1); atomicAdd(&my[B + (s4.z >> LB)], 1);
        atomicAdd(&my[d4.w >> LB], 1); atomicAdd(&my[B + (s4.w >> LB)], 1);
    }
    if (blockIdx.x == (int)gridDim.x - 1 && threadIdx.x == 0) {   // scalar tail
        for (int e = i4end << 2; e < end; ++e) {
            atomicAdd(&my[dst[e] >> LB], 1);
            atomicAdd(&my[B + (src[e] >> LB)], 1);
        }
    }
    __syncthreads();
    for (int i = threadIdx.x; i < nbins; i += blockDim.x) {
        int s = lh[i] + lh[nbins + i] + lh[2 * nbins + i] + lh[3 * nbins + i];
        if (i < B) counts[i * nb + blockIdx.x] = s;               // bin-major
        else       counts[M + (i - B) * nb + blockIdx.x] = s;
    }
}

__global__ void scan_block_kernel(int* __restrict__ data, int* __restrict__ blocksum, int M2) {
    __shared__ int lds[SCAN_BLK];
    int t = threadIdx.x;
    int i = blockIdx.x * SCAN_BLK + t;
    int v = (i < M2) ? data[i] : 0;
    lds[t] = v;
    __syncthreads();
    for (int off = 1; off < SCAN_BLK; off <<= 1) {
        int tmp = (t >= off) ? lds[t - off] : 0;
        __syncthreads();
        lds[t] += tmp;
        __syncthreads();
    }
    if (i < M2) data[i] = lds[t] - v;
    if (t == SCAN_BLK - 1) blocksum[blockIdx.x] = lds[t];
}

__global__ void scan_partials_kernel(const int* __restrict__ bsum, int* __restrict__ boff,
                                     int* __restrict__ ticket, int n) {
    __shared__ int lds[SCAN_BLK];
    __shared__ int carry_s;
    if (threadIdx.x == 0) { carry_s = 0; ticket[0] = 0; }  // reset final ticket
    __syncthreads();
    for (int base = 0; base < n; base += SCAN_BLK) {
        int i = base + threadIdx.x;
        int v = (i < n) ? bsum[i] : 0;
        lds[threadIdx.x] = v;
        __syncthreads();
        for (int off = 1; off < SCAN_BLK; off <<= 1) {
            int tmp = (threadIdx.x >= off) ? lds[threadIdx.x - off] : 0;
            __syncthreads();
            lds[threadIdx.x] += tmp;
            __syncthreads();
        }
        int incl = lds[threadIdx.x];
        int c = carry_s;
        if (i < n) boff[i] = c + incl - v;
        __syncthreads();
        if (threadIdx.x == SCAN_BLK - 1) carry_s = c + incl;
        __syncthreads();
    }
}

__global__ void fused_scatter_kernel(const int* __restrict__ src, const int* __restrict__ dst,
                                     const int* __restrict__ counts, const int* __restrict__ boff,
                                     unsigned* __restrict__ packed, unsigned short* __restrict__ psrc,
                                     int E, int B, int nb, int M) {
    extern __shared__ int loff[];            // [0,B): dst cursors, [B,2B): src cursors
    int b = blockIdx.x;
    for (int i = threadIdx.x; i < B; i += blockDim.x) {
        int id  = i * nb + b;
        int id2 = M + i * nb + b;
        loff[i]     = counts[id]  + boff[id >> 10];
        loff[B + i] = counts[id2] + boff[id2 >> 10] - E;   // src half starts at E
    }
    __syncthreads();
    int base = b * CHUNK;
    int end  = base + CHUNK < E ? base + CHUNK : E;
    int i4beg = base >> 2, i4end = end >> 2;
    for (int i = i4beg + threadIdx.x; i < i4end; i += blockDim.x) {
        int4 s4 = ((const int4*)src)[i];
        int4 d4 = ((const int4*)dst)[i];
        #pragma unroll
        for (int k = 0; k < 4; ++k) {
            int s = (k == 0) ? s4.x : (k == 1) ? s4.y : (k == 2) ? s4.z : s4.w;
            int d = (k == 0) ? d4.x : (k == 1) ? d4.y : (k == 2) ? d4.z : d4.w;
            int pos = atomicAdd(&loff[d >> LB], 1);
            packed[pos] = (unsigned)s | ((unsigned)(d & (BN - 1)) << 17);
            int pos2 = atomicAdd(&loff[B + (s >> LB)], 1);
            psrc[pos2] = (unsigned short)(s & (BN - 1));
        }
    }
    if (b == (int)gridDim.x - 1 && threadIdx.x == 0) {     // scalar tail
        for (int e = i4end << 2; e < end; ++e) {
            int s = src[e], d = dst[e];
            int pos = atomicAdd(&loff[d >> LB], 1);
            packed[pos] = (unsigned)s | ((unsigned)(d & (BN - 1)) << 17);
            int pos2 = atomicAdd(&loff[B + (s >> LB)], 1);
            psrc[pos2] = (unsigned short)(s & (BN - 1));
        }
    }
}

// Fused: (A) src-bucket count -> invdeg, rA; (B) dst-bucket counting sort ->
// csr_src, row_ptr. One block per bucket, BN threads, 8x replicated counters.
__global__ void bucket_kernel(const unsigned short* __restrict__ psrc,
                              const unsigned* __restrict__ packed,
                              const int* __restrict__ counts, const int* __restrict__ boff,
                              float* __restrict__ invdeg, float* __restrict__ rA,
                              int* __restrict__ csr_src, int* __restrict__ row_ptr,
                              int N, int E, int B, int nb, int M) {
    __shared__ int cnt[8 * BN];
    __shared__ int off[BN];
    int t = threadIdx.x, b = blockIdx.x, w = t >> 6;
    int g = (b << LB) + t;
    // ---- phase A: src fine count -> invdeg, r0
    for (int i = t; i < 8 * BN; i += blockDim.x) cnt[i] = 0;
    __syncthreads();
    int id = M + b * nb;
    int beg = counts[id] + boff[id >> 10] - E;
    int end;
    if (b + 1 < B) { int id2 = M + (b + 1) * nb; end = counts[id2] + boff[id2 >> 10] - E; }
    else end = E;
    for (int e = beg + t; e < end; e += blockDim.x)
        atomicAdd(&cnt[(w << 9) + psrc[e]], 1);
    __syncthreads();
    if (g < N) {
        int tot = 0;
        #pragma unroll
        for (int r = 0; r < 8; ++r) tot += cnt[(r << 9) + t];
        float v = 1.0f / ((float)tot + 1e-9f);
        invdeg[g] = v;
        rA[g] = v;                 // r_0 = 1 * invdeg
    }
    __syncthreads();
    // ---- phase B: dst counting sort
    for (int i = t; i < 8 * BN; i += blockDim.x) cnt[i] = 0;
    __syncthreads();
    id = b * nb;
    beg = counts[id] + boff[id >> 10];
    if (b + 1 < B) { int id2 = (b + 1) * nb; end = counts[id2] + boff[id2 >> 10]; }
    else end = E;
    for (int e = beg + t; e < end; e += blockDim.x)
        atomicAdd(&cnt[(w << 9) + (packed[e] >> 17)], 1);
    __syncthreads();
    int tot = 0;
    #pragma unroll
    for (int r = 0; r < 8; ++r) tot += cnt[(r << 9) + t];
    off[t] = tot;
    __syncthreads();
    for (int s = 1; s < BN; s <<= 1) {            // Hillis-Steele inclusive
        int v = (t >= s) ? off[t - s] : 0;
        __syncthreads();
        off[t] += v;
        __syncthreads();
    }
    int excl = beg + off[t] - tot;
    if (g < N) row_ptr[g] = excl;
    {
        int base2 = excl;                          // per-wave pre-reserved cursors
        #pragma unroll
        for (int r = 0; r < 8; ++r) { int c = cnt[(r << 9) + t]; cnt[(r << 9) + t] = base2; base2 += c; }
    }
    __syncthreads();
    for (int e = beg + t; e < end; e += blockDim.x) {
        unsigned v = packed[e];
        int pos = atomicAdd(&cnt[(w << 9) + (v >> 17)], 1);
        csr_src[pos] = (int)(v & 0x1FFFFu);
    }
    if (b == 0 && t == 0) row_ptr[N] = E;
}

// ---------- flow loop: quad-lane per node, atomic-free ----------

__global__ void spmv_q_kernel(const int* __restrict__ row_ptr, const int* __restrict__ csr_src,
                              const float* __restrict__ r_in, const float* __restrict__ d0,
                              const float* __restrict__ invdeg, float* __restrict__ r_out, int N) {
    int tid = blockIdx.x * blockDim.x + threadIdx.x;
    int n = tid >> 2;
    if (n >= N) return;
    int q = tid & 3;
    int beg = row_ptr[n], end = row_ptr[n + 1];
    int len = end - beg;
    int lo = beg + ((len * q) >> 2);
    int hi = beg + ((len * (q + 1)) >> 2);
    float a = 0.0f;
    for (int j = lo; j < hi; ++j) a += r_in[csr_src[j]];
    a += __shfl_xor(a, 1, 64);
    a += __shfl_xor(a, 2, 64);
    if (q == 0) {
        float p = a - d0[n];
        p = p > 0.0f ? p : 0.0f;
        r_out[n] = p * invdeg[n];
    }
}

// final: flow/fw/cost; cost reduced by last-finished block (threadfence ticket).
__global__ void final_kernel(const int* __restrict__ src, const float* __restrict__ r_fin,
                             const float* __restrict__ invdeg, float* __restrict__ flow,
                             float* __restrict__ fw, float* __restrict__ partials,
                             int* __restrict__ ticket, float* __restrict__ cost, int E) {
    int i = blockIdx.x * blockDim.x + threadIdx.x;
    int E4 = E >> 2;
    float f2 = 0.0f;
    if (i < E4) {
        int4 s4 = ((const int4*)src)[i];
        float a = r_fin[s4.x], b = r_fin[s4.y], c = r_fin[s4.z], d = r_fin[s4.w];
        int e = i << 2;
        flow[e] = a; flow[e + 1] = b; flow[e + 2] = c; flow[e + 3] = d;
        fw[e] = invdeg[s4.x]; fw[e + 1] = invdeg[s4.y];
        fw[e + 2] = invdeg[s4.z]; fw[e + 3] = invdeg[s4.w];
        f2 = a * a + b * b + c * c + d * d;
    }
    if (blockIdx.x == 0 && threadIdx.x == 0) {   // tail (E % 4)
        for (int e = E4 << 2; e < E; ++e) {
            float a = r_fin[src[e]];
            flow[e] = a; fw[e] = invdeg[src[e]];
            f2 += a * a;
        }
    }
    #pragma unroll
    for (int off = 32; off > 0; off >>= 1) f2 += __shfl_down(f2, off, 64);
    __shared__ float wsum[BLK / 64];
    int lane = threadIdx.x & 63, w = threadIdx.x >> 6;
    if (lane == 0) wsum[w] = f2;
    __syncthreads();
    __shared__ bool amLast;
    if (threadIdx.x == 0) {
        float s = 0.0f;
        #pragma unroll
        for (int k = 0; k < BLK / 64; ++k) s += wsum[k];
        partials[blockIdx.x] = s;
        __threadfence();                                   // publish partial
        int prev = atomicAdd(ticket, 1);                   // device-scope
        amLast = (prev == (int)gridDim.x - 1);
    }
    __syncthreads();
    if (amLast) {                                          // deterministic sum order
        __threadfence();
        float s = 0.0f;
        for (int k = threadIdx.x; k < (int)gridDim.x; k += blockDim.x) s += partials[k];
        #pragma unroll
        for (int off = 32; off > 0; off >>= 1) s += __shfl_down(s, off, 64);
        __shared__ float wsum2[BLK / 64];
        if (lane == 0) wsum2[w] = s;
        __syncthreads();
        if (threadIdx.x == 0) {
            float t2 = 0.0f;
            #pragma unroll
            for (int k = 0; k < BLK / 64; ++k) t2 += wsum2[k];
            cost[0] = t2;
        }
    }
}

extern "C" void kernel_launch(void* const* d_in, const int* in_sizes, int n_in,
                              void* d_out, int out_size, void* d_ws, size_t ws_size,
                              hipStream_t stream) {
    const float* demands  = (const float*)d_in[0];
    const int*   edge_src = (const int*)d_in[2];
    const int*   edge_dst = (const int*)d_in[3];
    const int N = in_sizes[0];
    const int E = in_sizes[2];

    float* out  = (float*)d_out;
    float* cost = out;
    float* flow = out + 1;
    float* fw   = out + 1 + E;

    const int B   = (N + BN - 1) >> LB;              // 196 buckets
    const int nb  = (E + CHUNK - 1) / CHUNK;         // 391 partition blocks
    const int M   = B * nb;
    const int M2  = 2 * M;                           // ~153K
    const int nbs = (M2 + SCAN_BLK - 1) / SCAN_BLK;
    const int gridF = ((E >> 2) + BLK - 1) / BLK;    // final (vec4)
    const int gridS = (4 * N + BLK - 1) / BLK;       // spmv (quad-lane/node)

    auto align16 = [](size_t x) { return (x + 15) & ~size_t(15); };
    char* ws = (char*)d_ws;
    size_t o = 0;
    float*    invdeg   = (float*)(ws + o);    o += align16((size_t)N * 4);
    float*    rA       = (float*)(ws + o);    o += align16((size_t)N * 4);
    float*    rB       = (float*)(ws + o);    o += align16((size_t)N * 4);
    int*      row_ptr  = (int*)(ws + o);      o += align16((size_t)(N + 1) * 4);
    int*      counts   = (int*)(ws + o);      o += align16((size_t)M2 * 4);
    int*      blocksum = (int*)(ws + o);      o += align16((size_t)nbs * 4);
    int*      blockoff = (int*)(ws + o);      o += align16((size_t)nbs * 4);
    int*      ticket   = (int*)(ws + o);      o += align16(4);
    unsigned* packed   = (unsigned*)(ws + o); o += align16((size_t)E * 4);
    unsigned short* psrc = (unsigned short*)(ws + o); o += align16((size_t)E * 2);
    int*      csr_src  = (int*)(ws + o);      o += align16((size_t)E * 4);
    float*    partials = (float*)(ws + o);    o += align16((size_t)gridF * 4);

    hist_kernel<<<nb, BLK, (size_t)(8 * B) * 4, stream>>>(edge_src, edge_dst, counts, E, B, nb, M);
    scan_block_kernel<<<nbs, SCAN_BLK, 0, stream>>>(counts, blocksum, M2);
    scan_partials_kernel<<<1, SCAN_BLK, 0, stream>>>(blocksum, blockoff, ticket, nbs);
    fused_scatter_kernel<<<nb, BLK, (size_t)(2 * B) * 4, stream>>>(
        edge_src, edge_dst, counts, blockoff, packed, psrc, E, B, nb, M);
    bucket_kernel<<<B, BN, 0, stream>>>(psrc, packed, counts, blockoff,
                                        invdeg, rA, csr_src, row_ptr, N, E, B, nb, M);

    float* r_cur = rA;
    float* r_nxt = rB;
    for (int it = 0; it < 10; ++it) {
        spmv_q_kernel<<<gridS, BLK, 0, stream>>>(row_ptr, csr_src, r_cur, demands, invdeg, r_nxt, N);
        float* t = r_cur; r_cur = r_nxt; r_nxt = t;
    }

    final_kernel<<<gridF, BLK, 0, stream>>>(edge_src, r_cur, invdeg, flow, fw,
                                            partials, ticket, cost, E);
}

// Round 9
// 171.819 us; speedup vs baseline: 6.9149x; 1.3374x over previous
//
#include <hip/hip_runtime.h>

// SparseMCFModel: the GNN is dead code. fw_e = 1/(outdeg(src_e)+1e-9) exactly
// (softmax over per-segment-constant scores). Flow loop collapses to node
// space: r_0 = invdeg; r_{k+1}[n] = relu(sum_{e:dst=n} r_k[src_e] - d0[n]) *
// invdeg[n]; flow[e] = r_10[src[e]]; fw[e] = invdeg[src[e]]; cost = sum flow^2.
//
// R1->R2: no single-address cost atomic; CSR gather spmv.       1268 -> 428 us
// R2->R3: bucket partition (atomic-free except outdeg hist).     428 -> 284 us
// R3->R4: zero global atomics, CHUNK 4096.                       284 -> 219 us
// R4->R5: full counting sort -> CSR-by-dst, atomic-free spmv.    219 -> 220 us
// R5->R6: 8x smaller counts matrix, fused scatter, replicated
//   LDS counters, fused bucket pass, float2 carry.               220 -> 188 us
// R6->R7: cooperative grid.sync — ~100us/sync (XCD non-coherence). -> 1188 us
// R7->R8: multi-kernel again + quad-lane spmv, BUT threadfence-ticket in
//   final = 6250 same-address device atomics x ~13ns = 80us.     -> 230 us
// R8->R9: drop ticket (separate 3us reduce kernel). Last spmv iteration
//   writes float2{r10, invdeg} (it loads invdeg anyway) so final serves
//   flow AND fw from ONE 8B gather — iters 0..8 keep cheap 4B gathers.
//   Same-address device atomics: ZERO anywhere. grid.sync: none.

static constexpr int BLK      = 256;
static constexpr int SCAN_BLK = 1024;
static constexpr int CHUNK    = 4096;   // edges per partition block
static constexpr int LB       = 9;      // log2(nodes per bucket)
static constexpr int BN       = 512;    // nodes per bucket

// ---------- build passes ----------

__global__ void hist_kernel(const int* __restrict__ src, const int* __restrict__ dst,
                            int* __restrict__ counts, int E, int B, int nb, int M) {
    extern __shared__ int lh[];              // 4 replicas x [0,B) dst | [B,2B) src
    const int nbins = 2 * B;
    for (int i = threadIdx.x; i < 4 * nbins; i += blockDim.x) lh[i] = 0;
    __syncthreads();
    int* my = lh + (threadIdx.x >> 6) * nbins;
    int base = blockIdx.x * CHUNK;
    int end  = base + CHUNK < E ? base + CHUNK : E;
    int i4beg = base >> 2, i4end = end >> 2;
    for (int i = i4beg + threadIdx.x; i < i4end; i += blockDim.x) {
        int4 s4 = ((const int4*)src)[i];
        int4 d4 = ((const int4*)dst)[i];
        atomicAdd(&my[d4.x >> LB], 1); atomicAdd(&my[B + (s4.x >> LB)], 1);
        atomicAdd(&my[d4.y >> LB], 1); atomicAdd(&my[B + (s4.y >> LB)], 1);
        atomicAdd(&my[d4.z >> LB], 1); atomicAdd(&my[B + (s4.z >> LB)], 1);
        atomicAdd(&my[d4.w >> LB], 1); atomicAdd(&my[B + (s4.w >> LB)], 1);
    }
    if (blockIdx.x == (int)gridDim.x - 1 && threadIdx.x == 0) {   // scalar tail
        for (int e = i4end << 2; e < end; ++e) {
            atomicAdd(&my[dst[e] >> LB], 1);
            atomicAdd(&my[B + (src[e] >> LB)], 1);
        }
    }
    __syncthreads();
    for (int i = threadIdx.x; i < nbins; i += blockDim.x) {
        int s = lh[i] + lh[nbins + i] + lh[2 * nbins + i] + lh[3 * nbins + i];
        if (i < B) counts[i * nb + blockIdx.x] = s;               // bin-major
        else       counts[M + (i - B) * nb + blockIdx.x] = s;
    }
}

__global__ void scan_block_kernel(int* __restrict__ data, int* __restrict__ blocksum, int M2) {
    __shared__ int lds[SCAN_BLK];
    int t = threadIdx.x;
    int i = blockIdx.x * SCAN_BLK + t;
    int v = (i < M2) ? data[i] : 0;
    lds[t] = v;
    __syncthreads();
    for (int off = 1; off < SCAN_BLK; off <<= 1) {
        int tmp = (t >= off) ? lds[t - off] : 0;
        __syncthreads();
        lds[t] += tmp;
        __syncthreads();
    }
    if (i < M2) data[i] = lds[t] - v;
    if (t == SCAN_BLK - 1) blocksum[blockIdx.x] = lds[t];
}

__global__ void scan_partials_kernel(const int* __restrict__ bsum, int* __restrict__ boff, int n) {
    __shared__ int lds[SCAN_BLK];
    __shared__ int carry_s;
    if (threadIdx.x == 0) carry_s = 0;
    __syncthreads();
    for (int base = 0; base < n; base += SCAN_BLK) {
        int i = base + threadIdx.x;
        int v = (i < n) ? bsum[i] : 0;
        lds[threadIdx.x] = v;
        __syncthreads();
        for (int off = 1; off < SCAN_BLK; off <<= 1) {
            int tmp = (threadIdx.x >= off) ? lds[threadIdx.x - off] : 0;
            __syncthreads();
            lds[threadIdx.x] += tmp;
            __syncthreads();
        }
        int incl = lds[threadIdx.x];
        int c = carry_s;
        if (i < n) boff[i] = c + incl - v;
        __syncthreads();
        if (threadIdx.x == SCAN_BLK - 1) carry_s = c + incl;
        __syncthreads();
    }
}

__global__ void fused_scatter_kernel(const int* __restrict__ src, const int* __restrict__ dst,
                                     const int* __restrict__ counts, const int* __restrict__ boff,
                                     unsigned* __restrict__ packed, unsigned short* __restrict__ psrc,
                                     int E, int B, int nb, int M) {
    extern __shared__ int loff[];            // [0,B): dst cursors, [B,2B): src cursors
    int b = blockIdx.x;
    for (int i = threadIdx.x; i < B; i += blockDim.x) {
        int id  = i * nb + b;
        int id2 = M + i * nb + b;
        loff[i]     = counts[id]  + boff[id >> 10];
        loff[B + i] = counts[id2] + boff[id2 >> 10] - E;   // src half starts at E
    }
    __syncthreads();
    int base = b * CHUNK;
    int end  = base + CHUNK < E ? base + CHUNK : E;
    int i4beg = base >> 2, i4end = end >> 2;
    for (int i = i4beg + threadIdx.x; i < i4end; i += blockDim.x) {
        int4 s4 = ((const int4*)src)[i];
        int4 d4 = ((const int4*)dst)[i];
        #pragma unroll
        for (int k = 0; k < 4; ++k) {
            int s = (k == 0) ? s4.x : (k == 1) ? s4.y : (k == 2) ? s4.z : s4.w;
            int d = (k == 0) ? d4.x : (k == 1) ? d4.y : (k == 2) ? d4.z : d4.w;
            int pos = atomicAdd(&loff[d >> LB], 1);
            packed[pos] = (unsigned)s | ((unsigned)(d & (BN - 1)) << 17);
            int pos2 = atomicAdd(&loff[B + (s >> LB)], 1);
            psrc[pos2] = (unsigned short)(s & (BN - 1));
        }
    }
    if (b == (int)gridDim.x - 1 && threadIdx.x == 0) {     // scalar tail
        for (int e = i4end << 2; e < end; ++e) {
            int s = src[e], d = dst[e];
            int pos = atomicAdd(&loff[d >> LB], 1);
            packed[pos] = (unsigned)s | ((unsigned)(d & (BN - 1)) << 17);
            int pos2 = atomicAdd(&loff[B + (s >> LB)], 1);
            psrc[pos2] = (unsigned short)(s & (BN - 1));
        }
    }
}

// Fused: (A) src-bucket count -> invdeg, rA; (B) dst-bucket counting sort ->
// csr_src, row_ptr. One block per bucket, BN threads, 8x replicated counters.
__global__ void bucket_kernel(const unsigned short* __restrict__ psrc,
                              const unsigned* __restrict__ packed,
                              const int* __restrict__ counts, const int* __restrict__ boff,
                              float* __restrict__ invdeg, float* __restrict__ rA,
                              int* __restrict__ csr_src, int* __restrict__ row_ptr,
                              int N, int E, int B, int nb, int M) {
    __shared__ int cnt[8 * BN];
    __shared__ int off[BN];
    int t = threadIdx.x, b = blockIdx.x, w = t >> 6;
    int g = (b << LB) + t;
    // ---- phase A: src fine count -> invdeg, r0
    for (int i = t; i < 8 * BN; i += blockDim.x) cnt[i] = 0;
    __syncthreads();
    int id = M + b * nb;
    int beg = counts[id] + boff[id >> 10] - E;
    int end;
    if (b + 1 < B) { int id2 = M + (b + 1) * nb; end = counts[id2] + boff[id2 >> 10] - E; }
    else end = E;
    for (int e = beg + t; e < end; e += blockDim.x)
        atomicAdd(&cnt[(w << 9) + psrc[e]], 1);
    __syncthreads();
    if (g < N) {
        int tot = 0;
        #pragma unroll
        for (int r = 0; r < 8; ++r) tot += cnt[(r << 9) + t];
        float v = 1.0f / ((float)tot + 1e-9f);
        invdeg[g] = v;
        rA[g] = v;                 // r_0 = 1 * invdeg
    }
    __syncthreads();
    // ---- phase B: dst counting sort
    for (int i = t; i < 8 * BN; i += blockDim.x) cnt[i] = 0;
    __syncthreads();
    id = b * nb;
    beg = counts[id] + boff[id >> 10];
    if (b + 1 < B) { int id2 = (b + 1) * nb; end = counts[id2] + boff[id2 >> 10]; }
    else end = E;
    for (int e = beg + t; e < end; e += blockDim.x)
        atomicAdd(&cnt[(w << 9) + (packed[e] >> 17)], 1);
    __syncthreads();
    int tot = 0;
    #pragma unroll
    for (int r = 0; r < 8; ++r) tot += cnt[(r << 9) + t];
    off[t] = tot;
    __syncthreads();
    for (int s = 1; s < BN; s <<= 1) {            // Hillis-Steele inclusive
        int v = (t >= s) ? off[t - s] : 0;
        __syncthreads();
        off[t] += v;
        __syncthreads();
    }
    int excl = beg + off[t] - tot;
    if (g < N) row_ptr[g] = excl;
    {
        int base2 = excl;                          // per-wave pre-reserved cursors
        #pragma unroll
        for (int r = 0; r < 8; ++r) { int c = cnt[(r << 9) + t]; cnt[(r << 9) + t] = base2; base2 += c; }
    }
    __syncthreads();
    for (int e = beg + t; e < end; e += blockDim.x) {
        unsigned v = packed[e];
        int pos = atomicAdd(&cnt[(w << 9) + (v >> 17)], 1);
        csr_src[pos] = (int)(v & 0x1FFFFu);
    }
    if (b == 0 && t == 0) row_ptr[N] = E;
}

// ---------- flow loop: quad-lane per node, atomic-free ----------
// LAST=false: write plain float r. LAST=true: write float2{r, invdeg}.
template <bool LAST>
__global__ void spmv_q_kernel(const int* __restrict__ row_ptr, const int* __restrict__ csr_src,
                              const float* __restrict__ r_in, const float* __restrict__ d0,
                              const float* __restrict__ invdeg, float* __restrict__ r_out,
                              float2* __restrict__ rz_out, int N) {
    int tid = blockIdx.x * blockDim.x + threadIdx.x;
    int n = tid >> 2;
    if (n >= N) return;
    int q = tid & 3;
    int beg = row_ptr[n], end = row_ptr[n + 1];
    int len = end - beg;
    int lo = beg + ((len * q) >> 2);
    int hi = beg + ((len * (q + 1)) >> 2);
    float a = 0.0f;
    for (int j = lo; j < hi; ++j) a += r_in[csr_src[j]];
    a += __shfl_xor(a, 1, 64);
    a += __shfl_xor(a, 2, 64);
    if (q == 0) {
        float inv = invdeg[n];
        float p = a - d0[n];
        p = p > 0.0f ? p : 0.0f;
        if (LAST) rz_out[n] = make_float2(p * inv, inv);
        else      r_out[n] = p * inv;
    }
}

// flow[e]=rz.x, fw[e]=rz.y from ONE 8B gather; per-block partial of flow^2.
__global__ void final_kernel(const int* __restrict__ src, const float2* __restrict__ rz,
                             float* __restrict__ flow, float* __restrict__ fw,
                             float* __restrict__ partials, int E) {
    int i = blockIdx.x * blockDim.x + threadIdx.x;
    int E4 = E >> 2;
    float f2 = 0.0f;
    if (i < E4) {
        int4 s4 = ((const int4*)src)[i];
        float2 a = rz[s4.x], b = rz[s4.y], c = rz[s4.z], d = rz[s4.w];
        int e = i << 2;
        flow[e] = a.x; flow[e + 1] = b.x; flow[e + 2] = c.x; flow[e + 3] = d.x;
        fw[e]   = a.y; fw[e + 1]   = b.y; fw[e + 2]   = c.y; fw[e + 3]   = d.y;
        f2 = a.x * a.x + b.x * b.x + c.x * c.x + d.x * d.x;
    }
    if (blockIdx.x == 0 && threadIdx.x == 0) {   // tail (E % 4)
        for (int e = E4 << 2; e < E; ++e) {
            float2 a = rz[src[e]];
            flow[e] = a.x; fw[e] = a.y;
            f2 += a.x * a.x;
        }
    }
    #pragma unroll
    for (int off = 32; off > 0; off >>= 1) f2 += __shfl_down(f2, off, 64);
    __shared__ float wsum[BLK / 64];
    int lane = threadIdx.x & 63, w = threadIdx.x >> 6;
    if (lane == 0) wsum[w] = f2;
    __syncthreads();
    if (threadIdx.x == 0) {
        float s = 0.0f;
        #pragma unroll
        for (int k = 0; k < BLK / 64; ++k) s += wsum[k];
        partials[blockIdx.x] = s;
    }
}

__global__ void reduce_cost_kernel(const float* __restrict__ partials, float* __restrict__ cost, int n) {
    float s = 0.0f;
    for (int i = threadIdx.x; i < n; i += blockDim.x) s += partials[i];
    #pragma unroll
    for (int off = 32; off > 0; off >>= 1) s += __shfl_down(s, off, 64);
    __shared__ float wsum[16];
    int lane = threadIdx.x & 63, w = threadIdx.x >> 6;
    if (lane == 0) wsum[w] = s;
    __syncthreads();
    if (threadIdx.x == 0) {
        float t = 0.0f;
        for (int k = 0; k < (int)(blockDim.x / 64); ++k) t += wsum[k];
        cost[0] = t;
    }
}

extern "C" void kernel_launch(void* const* d_in, const int* in_sizes, int n_in,
                              void* d_out, int out_size, void* d_ws, size_t ws_size,
                              hipStream_t stream) {
    const float* demands  = (const float*)d_in[0];
    const int*   edge_src = (const int*)d_in[2];
    const int*   edge_dst = (const int*)d_in[3];
    const int N = in_sizes[0];
    const int E = in_sizes[2];

    float* out  = (float*)d_out;
    float* cost = out;
    float* flow = out + 1;
    float* fw   = out + 1 + E;

    const int B   = (N + BN - 1) >> LB;              // 196 buckets
    const int nb  = (E + CHUNK - 1) / CHUNK;         // 391 partition blocks
    const int M   = B * nb;
    const int M2  = 2 * M;                           // ~153K
    const int nbs = (M2 + SCAN_BLK - 1) / SCAN_BLK;
    const int gridF = ((E >> 2) + BLK - 1) / BLK;    // final (vec4)
    const int gridS = (4 * N + BLK - 1) / BLK;       // spmv (quad-lane/node)

    auto align16 = [](size_t x) { return (x + 15) & ~size_t(15); };
    char* ws = (char*)d_ws;
    size_t o = 0;
    float*    invdeg   = (float*)(ws + o);    o += align16((size_t)N * 4);
    float*    rA       = (float*)(ws + o);    o += align16((size_t)N * 4);
    float*    rB       = (float*)(ws + o);    o += align16((size_t)N * 4);
    float2*   rz2      = (float2*)(ws + o);   o += align16((size_t)N * 8);
    int*      row_ptr  = (int*)(ws + o);      o += align16((size_t)(N + 1) * 4);
    int*      counts   = (int*)(ws + o);      o += align16((size_t)M2 * 4);
    int*      blocksum = (int*)(ws + o);      o += align16((size_t)nbs * 4);
    int*      blockoff = (int*)(ws + o);      o += align16((size_t)nbs * 4);
    unsigned* packed   = (unsigned*)(ws + o); o += align16((size_t)E * 4);
    unsigned short* psrc = (unsigned short*)(ws + o); o += align16((size_t)E * 2);
    int*      csr_src  = (int*)(ws + o);      o += align16((size_t)E * 4);
    float*    partials = (float*)(ws + o);    o += align16((size_t)gridF * 4);

    hist_kernel<<<nb, BLK, (size_t)(8 * B) * 4, stream>>>(edge_src, edge_dst, counts, E, B, nb, M);
    scan_block_kernel<<<nbs, SCAN_BLK, 0, stream>>>(counts, blocksum, M2);
    scan_partials_kernel<<<1, SCAN_BLK, 0, stream>>>(blocksum, blockoff, nbs);
    fused_scatter_kernel<<<nb, BLK, (size_t)(2 * B) * 4, stream>>>(
        edge_src, edge_dst, counts, blockoff, packed, psrc, E, B, nb, M);
    bucket_kernel<<<B, BN, 0, stream>>>(psrc, packed, counts, blockoff,
                                        invdeg, rA, csr_src, row_ptr, N, E, B, nb, M);

    float* r_cur = rA;
    float* r_nxt = rB;
    for (int it = 0; it < 9; ++it) {
        spmv_q_kernel<false><<<gridS, BLK, 0, stream>>>(row_ptr, csr_src, r_cur, demands,
                                                        invdeg, r_nxt, nullptr, N);
        float* t = r_cur; r_cur = r_nxt; r_nxt = t;
    }
    spmv_q_kernel<true><<<gridS, BLK, 0, stream>>>(row_ptr, csr_src, r_cur, demands,
                                                   invdeg, nullptr, rz2, N);

    final_kernel<<<gridF, BLK, 0, stream>>>(edge_src, rz2, flow, fw, partials, E);
    reduce_cost_kernel<<<1, 1024, 0, stream>>>(partials, cost, gridF);
}

// Round 10
// 170.445 us; speedup vs baseline: 6.9707x; 1.0081x over previous
//
#include <hip/hip_runtime.h>

// SparseMCFModel: the GNN is dead code. fw_e = 1/(outdeg(src_e)+1e-9) exactly
// (softmax over per-segment-constant scores). Flow loop collapses to node
// space: r_0 = invdeg; r_{k+1}[n] = relu(sum_{e:dst=n} r_k[src_e] - d0[n]) *
// invdeg[n]; flow[e] = r_10[src[e]]; fw[e] = invdeg[src[e]]; cost = sum flow^2.
//
// R1->R2: no single-address cost atomic; CSR gather spmv.       1268 -> 428 us
// R2->R3: bucket partition (atomic-free except outdeg hist).     428 -> 284 us
// R3->R4: zero global atomics, CHUNK 4096.                       284 -> 219 us
// R4->R5: full counting sort -> CSR-by-dst, atomic-free spmv.    219 -> 220 us
// R5->R6: 8x smaller counts matrix, fused scatter, replicated
//   LDS counters, fused bucket pass, float2 carry.               220 -> 188 us
// R6->R7: cooperative grid.sync — ~100us/sync (XCD non-coherence). -> 1188 us
// R7->R8: threadfence-ticket = same-address atomic serialization.  -> 230 us
// R8->R9: ticket dropped; last spmv iter emits float2{r10,invdeg}.  -> 172 us
// R9->R10: CHUNK 8192 + BLK 512 edge passes (counts matrix halved, longer
//   scatter runs); scan_partials kernel + blockoff buffer eliminated
//   (consumers do a local LDS scan of the 76-entry blocksum); dz=float2
//   {d0,invdeg} merges spmv epilogue loads. 17 -> 15 launches.

static constexpr int BLK      = 256;    // spmv / final / reduce
static constexpr int BLK_B    = 512;    // hist / scatter / bucket
static constexpr int SCAN_BLK = 1024;
static constexpr int CHUNK    = 8192;   // edges per partition block
static constexpr int LB       = 9;      // log2(nodes per bucket)
static constexpr int BN       = 512;    // nodes per bucket
static constexpr int MAXNBS   = 256;    // max scan blocks (nbs = 76 here)

// ---------- build passes ----------

// Pass 1: per-block LDS histograms over dst- and src-buckets, 8x replicated.
__global__ void hist_kernel(const int* __restrict__ src, const int* __restrict__ dst,
                            int* __restrict__ counts, int E, int B, int nb, int M) {
    extern __shared__ int lh[];              // 8 replicas x [0,B) dst | [B,2B) src
    const int nbins = 2 * B;
    for (int i = threadIdx.x; i < 8 * nbins; i += blockDim.x) lh[i] = 0;
    __syncthreads();
    int* my = lh + (threadIdx.x >> 6) * nbins;
    int base = blockIdx.x * CHUNK;
    int end  = base + CHUNK < E ? base + CHUNK : E;
    int i4beg = base >> 2, i4end = end >> 2;
    for (int i = i4beg + threadIdx.x; i < i4end; i += blockDim.x) {
        int4 s4 = ((const int4*)src)[i];
        int4 d4 = ((const int4*)dst)[i];
        atomicAdd(&my[d4.x >> LB], 1); atomicAdd(&my[B + (s4.x >> LB)], 1);
        atomicAdd(&my[d4.y >> LB], 1); atomicAdd(&my[B + (s4.y >> LB)], 1);
        atomicAdd(&my[d4.z >> LB], 1); atomicAdd(&my[B + (s4.z >> LB)], 1);
        atomicAdd(&my[d4.w >> LB], 1); atomicAdd(&my[B + (s4.w >> LB)], 1);
    }
    if (blockIdx.x == (int)gridDim.x - 1 && threadIdx.x == 0) {   // scalar tail
        for (int e = i4end << 2; e < end; ++e) {
            atomicAdd(&my[dst[e] >> LB], 1);
            atomicAdd(&my[B + (src[e] >> LB)], 1);
        }
    }
    __syncthreads();
    for (int i = threadIdx.x; i < nbins; i += blockDim.x) {
        int s = 0;
        #pragma unroll
        for (int r = 0; r < 8; ++r) s += lh[r * nbins + i];
        if (i < B) counts[i * nb + blockIdx.x] = s;               // bin-major
        else       counts[M + (i - B) * nb + blockIdx.x] = s;
    }
}

// exclusive scan of counts[M2] in place; per-chunk totals to blocksum.
// Consumers scan blocksum locally (nbs ~ 76 entries).
__global__ void scan_block_kernel(int* __restrict__ data, int* __restrict__ blocksum, int M2) {
    __shared__ int lds[SCAN_BLK];
    int t = threadIdx.x;
    int i = blockIdx.x * SCAN_BLK + t;
    int v = (i < M2) ? data[i] : 0;
    lds[t] = v;
    __syncthreads();
    for (int off = 1; off < SCAN_BLK; off <<= 1) {
        int tmp = (t >= off) ? lds[t - off] : 0;
        __syncthreads();
        lds[t] += tmp;
        __syncthreads();
    }
    if (i < M2) data[i] = lds[t] - v;
    if (t == SCAN_BLK - 1) blocksum[blockIdx.x] = lds[t];
}

// local exclusive scan of blocksum into sboff[MAXNBS] (call with >= MAXNBS threads)
__device__ __forceinline__ void local_boff_scan(const int* __restrict__ blocksum,
                                                int* __restrict__ sboff, int nbs, int t) {
    int own = 0;
    if (t < MAXNBS) { own = (t < nbs) ? blocksum[t] : 0; sboff[t] = own; }
    __syncthreads();
    for (int off = 1; off < MAXNBS; off <<= 1) {
        int v = (t < MAXNBS && t >= off) ? sboff[t - off] : 0;
        __syncthreads();
        if (t < MAXNBS) sboff[t] += v;
        __syncthreads();
    }
    if (t < MAXNBS) sboff[t] -= own;   // exclusive
    __syncthreads();
}

// Pass 2: FUSED scatter: packed edges by dst-bucket + src shorts by src-bucket.
__global__ void fused_scatter_kernel(const int* __restrict__ src, const int* __restrict__ dst,
                                     const int* __restrict__ counts, const int* __restrict__ blocksum,
                                     unsigned* __restrict__ packed, unsigned short* __restrict__ psrc,
                                     int E, int B, int nb, int M, int nbs) {
    extern __shared__ int smem[];            // loff[2B] | sboff[MAXNBS]
    int* loff  = smem;
    int* sboff = smem + 2 * B;
    int t = threadIdx.x, b = blockIdx.x;
    local_boff_scan(blocksum, sboff, nbs, t);
    for (int i = t; i < B; i += blockDim.x) {
        int id  = i * nb + b;
        int id2 = M + i * nb + b;
        loff[i]     = counts[id]  + sboff[id >> 10];
        loff[B + i] = counts[id2] + sboff[id2 >> 10] - E;   // src half starts at E
    }
    __syncthreads();
    int base = b * CHUNK;
    int end  = base + CHUNK < E ? base + CHUNK : E;
    int i4beg = base >> 2, i4end = end >> 2;
    for (int i = i4beg + t; i < i4end; i += blockDim.x) {
        int4 s4 = ((const int4*)src)[i];
        int4 d4 = ((const int4*)dst)[i];
        #pragma unroll
        for (int k = 0; k < 4; ++k) {
            int s = (k == 0) ? s4.x : (k == 1) ? s4.y : (k == 2) ? s4.z : s4.w;
            int d = (k == 0) ? d4.x : (k == 1) ? d4.y : (k == 2) ? d4.z : d4.w;
            int pos = atomicAdd(&loff[d >> LB], 1);
            packed[pos] = (unsigned)s | ((unsigned)(d & (BN - 1)) << 17);
            int pos2 = atomicAdd(&loff[B + (s >> LB)], 1);
            psrc[pos2] = (unsigned short)(s & (BN - 1));
        }
    }
    if (b == (int)gridDim.x - 1 && t == 0) {               // scalar tail
        for (int e = i4end << 2; e < end; ++e) {
            int s = src[e], d = dst[e];
            int pos = atomicAdd(&loff[d >> LB], 1);
            packed[pos] = (unsigned)s | ((unsigned)(d & (BN - 1)) << 17);
            int pos2 = atomicAdd(&loff[B + (s >> LB)], 1);
            psrc[pos2] = (unsigned short)(s & (BN - 1));
        }
    }
}

// Fused: (A) src-bucket count -> dz{d0,invdeg}, rA; (B) dst counting sort ->
// csr_src, row_ptr. One block per bucket, BN threads, 8x replicated counters.
__global__ void bucket_kernel(const unsigned short* __restrict__ psrc,
                              const unsigned* __restrict__ packed,
                              const int* __restrict__ counts, const int* __restrict__ blocksum,
                              const float* __restrict__ d0,
                              float2* __restrict__ dz, float* __restrict__ rA,
                              int* __restrict__ csr_src, int* __restrict__ row_ptr,
                              int N, int E, int B, int nb, int M, int nbs) {
    __shared__ int cnt[8 * BN];
    __shared__ int off[BN];
    __shared__ int sboff[MAXNBS];
    int t = threadIdx.x, b = blockIdx.x, w = t >> 6;
    int g = (b << LB) + t;
    local_boff_scan(blocksum, sboff, nbs, t);
    // ---- phase A: src fine count -> dz, r0
    for (int i = t; i < 8 * BN; i += blockDim.x) cnt[i] = 0;
    __syncthreads();
    int id = M + b * nb;
    int beg = counts[id] + sboff[id >> 10] - E;
    int end;
    if (b + 1 < B) { int id2 = M + (b + 1) * nb; end = counts[id2] + sboff[id2 >> 10] - E; }
    else end = E;
    for (int e = beg + t; e < end; e += blockDim.x)
        atomicAdd(&cnt[(w << 9) + psrc[e]], 1);
    __syncthreads();
    if (g < N) {
        int tot = 0;
        #pragma unroll
        for (int r = 0; r < 8; ++r) tot += cnt[(r << 9) + t];
        float v = 1.0f / ((float)tot + 1e-9f);
        dz[g] = make_float2(d0[g], v);
        rA[g] = v;                 // r_0 = 1 * invdeg
    }
    __syncthreads();
    // ---- phase B: dst counting sort
    for (int i = t; i < 8 * BN; i += blockDim.x) cnt[i] = 0;
    __syncthreads();
    id = b * nb;
    beg = counts[id] + sboff[id >> 10];
    if (b + 1 < B) { int id2 = (b + 1) * nb; end = counts[id2] + sboff[id2 >> 10]; }
    else end = E;
    for (int e = beg + t; e < end; e += blockDim.x)
        atomicAdd(&cnt[(w << 9) + (packed[e] >> 17)], 1);
    __syncthreads();
    int tot = 0;
    #pragma unroll
    for (int r = 0; r < 8; ++r) tot += cnt[(r << 9) + t];
    off[t] = tot;
    __syncthreads();
    for (int s = 1; s < BN; s <<= 1) {            // Hillis-Steele inclusive
        int v = (t >= s) ? off[t - s] : 0;
        __syncthreads();
        off[t] += v;
        __syncthreads();
    }
    int excl = beg + off[t] - tot;
    if (g < N) row_ptr[g] = excl;
    {
        int base2 = excl;                          // per-wave pre-reserved cursors
        #pragma unroll
        for (int r = 0; r < 8; ++r) { int c = cnt[(r << 9) + t]; cnt[(r << 9) + t] = base2; base2 += c; }
    }
    __syncthreads();
    for (int e = beg + t; e < end; e += blockDim.x) {
        unsigned v = packed[e];
        int pos = atomicAdd(&cnt[(w << 9) + (v >> 17)], 1);
        csr_src[pos] = (int)(v & 0x1FFFFu);
    }
    if (b == 0 && t == 0) row_ptr[N] = E;
}

// ---------- flow loop: quad-lane per node, atomic-free ----------
// LAST=false: write plain float r. LAST=true: write float2{r, invdeg}.
template <bool LAST>
__global__ void spmv_q_kernel(const int* __restrict__ row_ptr, const int* __restrict__ csr_src,
                              const float* __restrict__ r_in, const float2* __restrict__ dz,
                              float* __restrict__ r_out, float2* __restrict__ rz_out, int N) {
    int tid = blockIdx.x * blockDim.x + threadIdx.x;
    int n = tid >> 2;
    if (n >= N) return;
    int q = tid & 3;
    int beg = row_ptr[n], end = row_ptr[n + 1];
    int len = end - beg;
    int lo = beg + ((len * q) >> 2);
    int hi = beg + ((len * (q + 1)) >> 2);
    float a = 0.0f;
    for (int j = lo; j < hi; ++j) a += r_in[csr_src[j]];
    a += __shfl_xor(a, 1, 64);
    a += __shfl_xor(a, 2, 64);
    if (q == 0) {
        float2 dzn = dz[n];                      // one 8B load: {d0, invdeg}
        float p = a - dzn.x;
        p = p > 0.0f ? p : 0.0f;
        if (LAST) rz_out[n] = make_float2(p * dzn.y, dzn.y);
        else      r_out[n] = p * dzn.y;
    }
}

// flow[e]=rz.x, fw[e]=rz.y from ONE 8B gather; per-block partial of flow^2.
__global__ void final_kernel(const int* __restrict__ src, const float2* __restrict__ rz,
                             float* __restrict__ flow, float* __restrict__ fw,
                             float* __restrict__ partials, int E) {
    int i = blockIdx.x * blockDim.x + threadIdx.x;
    int E4 = E >> 2;
    float f2 = 0.0f;
    if (i < E4) {
        int4 s4 = ((const int4*)src)[i];
        float2 a = rz[s4.x], b = rz[s4.y], c = rz[s4.z], d = rz[s4.w];
        int e = i << 2;
        flow[e] = a.x; flow[e + 1] = b.x; flow[e + 2] = c.x; flow[e + 3] = d.x;
        fw[e]   = a.y; fw[e + 1]   = b.y; fw[e + 2]   = c.y; fw[e + 3]   = d.y;
        f2 = a.x * a.x + b.x * b.x + c.x * c.x + d.x * d.x;
    }
    if (blockIdx.x == 0 && threadIdx.x == 0) {   // tail (E % 4)
        for (int e = E4 << 2; e < E; ++e) {
            float2 a = rz[src[e]];
            flow[e] = a.x; fw[e] = a.y;
            f2 += a.x * a.x;
        }
    }
    #pragma unroll
    for (int off = 32; off > 0; off >>= 1) f2 += __shfl_down(f2, off, 64);
    __shared__ float wsum[BLK / 64];
    int lane = threadIdx.x & 63, w = threadIdx.x >> 6;
    if (lane == 0) wsum[w] = f2;
    __syncthreads();
    if (threadIdx.x == 0) {
        float s = 0.0f;
        #pragma unroll
        for (int k = 0; k < BLK / 64; ++k) s += wsum[k];
        partials[blockIdx.x] = s;
    }
}

__global__ void reduce_cost_kernel(const float* __restrict__ partials, float* __restrict__ cost, int n) {
    float s = 0.0f;
    for (int i = threadIdx.x; i < n; i += blockDim.x) s += partials[i];
    #pragma unroll
    for (int off = 32; off > 0; off >>= 1) s += __shfl_down(s, off, 64);
    __shared__ float wsum[16];
    int lane = threadIdx.x & 63, w = threadIdx.x >> 6;
    if (lane == 0) wsum[w] = s;
    __syncthreads();
    if (threadIdx.x == 0) {
        float t = 0.0f;
        for (int k = 0; k < (int)(blockDim.x / 64); ++k) t += wsum[k];
        cost[0] = t;
    }
}

extern "C" void kernel_launch(void* const* d_in, const int* in_sizes, int n_in,
                              void* d_out, int out_size, void* d_ws, size_t ws_size,
                              hipStream_t stream) {
    const float* demands  = (const float*)d_in[0];
    const int*   edge_src = (const int*)d_in[2];
    const int*   edge_dst = (const int*)d_in[3];
    const int N = in_sizes[0];
    const int E = in_sizes[2];

    float* out  = (float*)d_out;
    float* cost = out;
    float* flow = out + 1;
    float* fw   = out + 1 + E;

    const int B   = (N + BN - 1) >> LB;              // 196 buckets
    const int nb  = (E + CHUNK - 1) / CHUNK;         // 196 partition blocks
    const int M   = B * nb;
    const int M2  = 2 * M;                           // ~77K
    const int nbs = (M2 + SCAN_BLK - 1) / SCAN_BLK;  // 76 (< MAXNBS)
    const int gridF = ((E >> 2) + BLK - 1) / BLK;    // final (vec4)
    const int gridS = (4 * N + BLK - 1) / BLK;       // spmv (quad-lane/node)

    auto align16 = [](size_t x) { return (x + 15) & ~size_t(15); };
    char* ws = (char*)d_ws;
    size_t o = 0;
    float2*   dz       = (float2*)(ws + o);   o += align16((size_t)N * 8);
    float*    rA       = (float*)(ws + o);    o += align16((size_t)N * 4);
    float*    rB       = (float*)(ws + o);    o += align16((size_t)N * 4);
    float2*   rz2      = (float2*)(ws + o);   o += align16((size_t)N * 8);
    int*      row_ptr  = (int*)(ws + o);      o += align16((size_t)(N + 1) * 4);
    int*      counts   = (int*)(ws + o);      o += align16((size_t)M2 * 4);
    int*      blocksum = (int*)(ws + o);      o += align16((size_t)nbs * 4);
    unsigned* packed   = (unsigned*)(ws + o); o += align16((size_t)E * 4);
    unsigned short* psrc = (unsigned short*)(ws + o); o += align16((size_t)E * 2);
    int*      csr_src  = (int*)(ws + o);      o += align16((size_t)E * 4);
    float*    partials = (float*)(ws + o);    o += align16((size_t)gridF * 4);

    hist_kernel<<<nb, BLK_B, (size_t)(16 * B) * 4, stream>>>(edge_src, edge_dst, counts, E, B, nb, M);
    scan_block_kernel<<<(M2 + SCAN_BLK - 1) / SCAN_BLK, SCAN_BLK, 0, stream>>>(counts, blocksum, M2);
    fused_scatter_kernel<<<nb, BLK_B, (size_t)(2 * B + MAXNBS) * 4, stream>>>(
        edge_src, edge_dst, counts, blocksum, packed, psrc, E, B, nb, M, nbs);
    bucket_kernel<<<B, BN, 0, stream>>>(psrc, packed, counts, blocksum, demands,
                                        dz, rA, csr_src, row_ptr, N, E, B, nb, M, nbs);

    float* r_cur = rA;
    float* r_nxt = rB;
    for (int it = 0; it < 9; ++it) {
        spmv_q_kernel<false><<<gridS, BLK, 0, stream>>>(row_ptr, csr_src, r_cur, dz,
                                                        r_nxt, nullptr, N);
        float* t = r_cur; r_cur = r_nxt; r_nxt = t;
    }
    spmv_q_kernel<true><<<gridS, BLK, 0, stream>>>(row_ptr, csr_src, r_cur, dz,
                                                   nullptr, rz2, N);

    final_kernel<<<gridF, BLK, 0, stream>>>(edge_src, rz2, flow, fw, partials, E);
    reduce_cost_kernel<<<1, 1024, 0, stream>>>(partials, cost, gridF);
}